// Round 23
// baseline (144.071 us; speedup 1.0000x reference)
//
#include <hip/hip_runtime.h>
#include <math.h>

constexpr int Bb = 4, Cc = 64, Hh = 256, Ww = 256;
constexpr int RR = 4;             // output rows per block (amp 1.5x)
constexpr int NSTRIP = Hh / RR;   // 64
constexpr int NBLK = Bb * NSTRIP; // 256 entropy blocks = 1 per CU
constexpr int NPX = Bb * Hh * Ww; // 262144 output pixels
constexpr int NPX4 = NPX / 4;

#define LOG2E 1.44269504088896340736f

__device__ __forceinline__ unsigned int fenc(float f) {
  unsigned int u = __float_as_uint(f);
  return (u & 0x80000000u) ? ~u : (u | 0x80000000u);
}
__device__ __forceinline__ float fdec(unsigned int k) {
  return __uint_as_float((k & 0x80000000u) ? (k ^ 0x80000000u) : ~k);
}

// Rescaled entropy (affine-invariant under final min/max normalize):
//   e' = log2(s) - (sum u*a)/s,  u = v*log2e, a = 2^u, s = 3x3 box of a.
//
// Structure (r19, best 24.5us): block (64,16) = 16 waves, lane = 4 cols
// (float4 full row), ty = 4 channels, RR = 4 rows, grid = 256 = 1 block/CU,
// block-local min/max -> pm (non-atomic), then one norm dispatch.
//
// r23: paired-ILP channels (two independent exp/shfl/hsum chains per wave)
// WITH __launch_bounds__(1024, 1). r21 showed the allocator caps plain
// 1024-thr blocks at 64 VGPR (2-blocks/CU heuristic) and spilled the
// ~105-reg paired body (263MB scratch). min-waves=1 legalizes the
// 128-VGPR class that a single-resident 16-wave block permits (m69:
// 16 waves/CU <=> VGPR<=128), so the pairing gets its fair trial.
// All acc indices compile-time (r15).
template <bool CHK>
__device__ __forceinline__ void do_pair(const float* __restrict__ p0,
                                        const float* __restrict__ p1,
                                        int r0, int tx, float (&acc)[RR][4]) {
  float ha0[3][4], hb0[3][4], ha1[3][4], hb1[3][4];
#pragma unroll
  for (int j = 0; j < RR + 2; ++j) {
    const int row = r0 - 1 + j;
    float4 v0 = make_float4(0.f, 0.f, 0.f, 0.f);
    float4 v1 = make_float4(0.f, 0.f, 0.f, 0.f);
    if (!CHK || (row >= 0 && row < Hh)) {
      v0 = *reinterpret_cast<const float4*>(p0 + (size_t)row * Ww);
      v1 = *reinterpret_cast<const float4*>(p1 + (size_t)row * Ww);
    }
    const float* vp0 = &v0.x;
    const float* vp1 = &v1.x;
    float a0[4], b0[4], a1[4], b1[4];
#pragma unroll
    for (int i = 0; i < 4; ++i) {
      float u0 = vp0[i] * LOG2E;
      float u1 = vp1[i] * LOG2E;
      a0[i] = __builtin_amdgcn_exp2f(u0);
      a1[i] = __builtin_amdgcn_exp2f(u1);
      b0[i] = u0 * a0[i];
      b1[i] = u1 * a1[i];
    }
    float la0 = __shfl_up(a0[3], 1, 64),  la1 = __shfl_up(a1[3], 1, 64);
    float lb0 = __shfl_up(b0[3], 1, 64),  lb1 = __shfl_up(b1[3], 1, 64);
    float ra0 = __shfl_down(a0[0], 1, 64), ra1 = __shfl_down(a1[0], 1, 64);
    float rb0 = __shfl_down(b0[0], 1, 64), rb1 = __shfl_down(b1[0], 1, 64);
    la0 = (tx == 0) ? 1.f : la0;   lb0 = (tx == 0) ? 0.f : lb0;
    la1 = (tx == 0) ? 1.f : la1;   lb1 = (tx == 0) ? 0.f : lb1;
    ra0 = (tx == 63) ? 1.f : ra0;  rb0 = (tx == 63) ? 0.f : rb0;
    ra1 = (tx == 63) ? 1.f : ra1;  rb1 = (tx == 63) ? 0.f : rb1;
    const int s0 = j % 3;  // compile-time (loop unrolled)
    {
      float t01 = a0[0] + a0[1], t23 = a0[2] + a0[3];
      ha0[s0][0] = la0 + t01;  ha0[s0][1] = t01 + a0[2];
      ha0[s0][2] = a0[1] + t23; ha0[s0][3] = t23 + ra0;
    }
    {
      float t01 = b0[0] + b0[1], t23 = b0[2] + b0[3];
      hb0[s0][0] = lb0 + t01;  hb0[s0][1] = t01 + b0[2];
      hb0[s0][2] = b0[1] + t23; hb0[s0][3] = t23 + rb0;
    }
    {
      float t01 = a1[0] + a1[1], t23 = a1[2] + a1[3];
      ha1[s0][0] = la1 + t01;  ha1[s0][1] = t01 + a1[2];
      ha1[s0][2] = a1[1] + t23; ha1[s0][3] = t23 + ra1;
    }
    {
      float t01 = b1[0] + b1[1], t23 = b1[2] + b1[3];
      hb1[s0][0] = lb1 + t01;  hb1[s0][1] = t01 + b1[2];
      hb1[s0][2] = b1[1] + t23; hb1[s0][3] = t23 + rb1;
    }
    if (j >= 2) {
      const int orow = j - 2;   // compile-time
#pragma unroll
      for (int i = 0; i < 4; ++i) {
        float s_0 = ha0[0][i] + ha0[1][i] + ha0[2][i];
        float w_0 = hb0[0][i] + hb0[1][i] + hb0[2][i];
        float s_1 = ha1[0][i] + ha1[1][i] + ha1[2][i];
        float w_1 = hb1[0][i] + hb1[1][i] + hb1[2][i];
        float e0 = __builtin_amdgcn_logf(s_0) - w_0 * __builtin_amdgcn_rcpf(s_0);
        float e1 = __builtin_amdgcn_logf(s_1) - w_1 * __builtin_amdgcn_rcpf(s_1);
        acc[orow][i] += e0 + e1;
      }
    }
  }
}

template <int FB>
__global__ __launch_bounds__(1024, 1) void entropy_kernel(const float* __restrict__ x,
                                                          float* __restrict__ e,
                                                          float* __restrict__ pm,
                                                          unsigned int* __restrict__ stats) {
  const int bx = blockIdx.x;
  const int strip = bx & (NSTRIP - 1);
  const int b = bx >> 6;
  const int r0 = strip * RR;
  const int tx = threadIdx.x;   // 0..63
  const int ty = threadIdx.y;   // 0..15
  const int w0 = tx * 4;

  const size_t planeStride = (size_t)Hh * Ww;
  const float* xb = x + ((size_t)b * Cc + ty * 4) * planeStride + w0;
  const bool interior = (strip != 0) && (strip != NSTRIP - 1);

  float acc[RR][4];
#pragma unroll
  for (int o = 0; o < RR; ++o)
#pragma unroll
    for (int i = 0; i < 4; ++i) acc[o][i] = 0.f;

  if (interior) {
    do_pair<false>(xb,                   xb + planeStride,     r0, tx, acc);
    do_pair<false>(xb + 2 * planeStride, xb + 3 * planeStride, r0, tx, acc);
  } else {
    do_pair<true>(xb,                   xb + planeStride,     r0, tx, acc);
    do_pair<true>(xb + 2 * planeStride, xb + 3 * planeStride, r0, tx, acc);
  }

  // Reduce the 16 ty channel groups (64 KiB LDS; 1 block/CU).
  __shared__ float red[16][RR][4][64];
#pragma unroll
  for (int o = 0; o < RR; ++o)
#pragma unroll
    for (int i = 0; i < 4; ++i) red[ty][o][i][tx] = acc[o][i];
  __syncthreads();

  float mn = INFINITY, mx = -INFINITY;
  if (ty < RR) {
    const size_t px = (size_t)(b * Hh + r0 + ty) * Ww + w0;
    float vsum[4];
#pragma unroll
    for (int i = 0; i < 4; ++i) {
      float t = 0.f;
#pragma unroll
      for (int g = 0; g < 16; ++g) t += red[g][ty][i][tx];
      vsum[i] = t;
    }
    *reinterpret_cast<float4*>(e + px) =
        make_float4(vsum[0], vsum[1], vsum[2], vsum[3]);
    mn = fminf(fminf(vsum[0], vsum[1]), fminf(vsum[2], vsum[3]));
    mx = fmaxf(fmaxf(vsum[0], vsum[1]), fmaxf(vsum[2], vsum[3]));
#pragma unroll
    for (int off = 32; off > 0; off >>= 1) {
      mn = fminf(mn, __shfl_down(mn, off, 64));
      mx = fmaxf(mx, __shfl_down(mx, off, 64));
    }
  }
  __shared__ float smn[RR], smx[RR];
  if (ty < RR && tx == 0) { smn[ty] = mn; smx[ty] = mx; }
  __syncthreads();
  if (ty == 0 && tx == 0) {
    mn = fminf(fminf(smn[0], smn[1]), fminf(smn[2], smn[3]));
    mx = fmaxf(fmaxf(smx[0], smx[1]), fmaxf(smx[2], smx[3]));
    if (FB == 0) {
      pm[bx] = mn;           // every slot written -> no init
      pm[NBLK + bx] = mx;
    } else {
      atomicMin(&stats[b], fenc(mn));
      atomicMax(&stats[4 + b], fenc(mx));
    }
  }
}

// Reduce this batch's 64 pm pairs in one wave, then normalize.
__global__ __launch_bounds__(256) void norm_ws(float* __restrict__ e,
                                               const float* __restrict__ pm) {
  const int bx = blockIdx.x;
  const int b = bx >> 6;
  const int lane = threadIdx.x & 63;
  float mn = pm[b * 64 + lane];
  float mx = pm[NBLK + b * 64 + lane];
#pragma unroll
  for (int off = 32; off > 0; off >>= 1) {
    mn = fminf(mn, __shfl_down(mn, off, 64));
    mx = fmaxf(mx, __shfl_down(mx, off, 64));
  }
  mn = __shfl(mn, 0, 64);
  mx = __shfl(mx, 0, 64);
  const float inv = 1.0f / fmaxf(mx - mn, 1e-6f);

  const int t = bx * 256 + threadIdx.x;
  float4 v = reinterpret_cast<float4*>(e)[t];
  v.x = (v.x - mn) * inv;
  v.y = (v.y - mn) * inv;
  v.z = (v.z - mn) * inv;
  v.w = (v.w - mn) * inv;
  reinterpret_cast<float4*>(e)[t] = v;
}

// Fallback normalize from atomic stats.
__global__ __launch_bounds__(256) void norm_atomic(float* __restrict__ e,
                                                   const unsigned int* __restrict__ stats) {
  const int t = blockIdx.x * 256 + threadIdx.x;
  const int b = t >> 14;
  const float mn = fdec(stats[b]);
  const float mx = fdec(stats[4 + b]);
  const float inv = 1.0f / fmaxf(mx - mn, 1e-6f);
  float4 v = reinterpret_cast<float4*>(e)[t];
  v.x = (v.x - mn) * inv;
  v.y = (v.y - mn) * inv;
  v.z = (v.z - mn) * inv;
  v.w = (v.w - mn) * inv;
  reinterpret_cast<float4*>(e)[t] = v;
}

extern "C" void kernel_launch(void* const* d_in, const int* in_sizes, int n_in,
                              void* d_out, int out_size, void* d_ws, size_t ws_size,
                              hipStream_t stream) {
  const float* x = (const float*)d_in[0];
  float* out = (float*)d_out;

  const size_t ws_needed = (size_t)(2 * NBLK) * sizeof(float);  // 2 KB
  if (ws_size >= ws_needed) {
    float* pm = (float*)d_ws;  // [NBLK min][NBLK max]
    entropy_kernel<0><<<dim3(NBLK), dim3(64, 16), 0, stream>>>(x, out, pm, nullptr);
    norm_ws<<<dim3(NPX4 / 256), dim3(256), 0, stream>>>(out, pm);
  } else {
    unsigned int* stats = (unsigned int*)d_ws;  // 8 uints
    hipMemsetAsync(stats, 0xFF, 4 * sizeof(unsigned int), stream);
    hipMemsetAsync(stats + 4, 0x00, 4 * sizeof(unsigned int), stream);
    entropy_kernel<1><<<dim3(NBLK), dim3(64, 16), 0, stream>>>(x, out, nullptr, stats);
    norm_atomic<<<dim3(NPX4 / 256), dim3(256), 0, stream>>>(out, stats);
  }
}

// Round 24
// 42.860 us; speedup vs baseline: 3.3614x; 3.3614x over previous
//
#include <hip/hip_runtime.h>
#include <math.h>

constexpr int Bb = 4, Cc = 64, Hh = 256, Ww = 256;
constexpr int RR = 4;             // output rows per block (amp 1.5x)
constexpr int CS = 2;             // channel split (32 ch per block)
constexpr int NSTRIP = Hh / RR;   // 64
constexpr int NPX = Bb * Hh * Ww; // 262144 output pixels
constexpr int NPX4 = NPX / 4;

#define LOG2E 1.44269504088896340736f

__device__ __forceinline__ unsigned int fenc(float f) {
  unsigned int u = __float_as_uint(f);
  return (u & 0x80000000u) ? ~u : (u | 0x80000000u);
}
__device__ __forceinline__ float fdec(unsigned int k) {
  return __uint_as_float((k & 0x80000000u) ? (k ^ 0x80000000u) : ~k);
}

// Rescaled entropy (affine-invariant under final min/max normalize):
//   e' = log2(s) - (sum u*a)/s,  u = v*log2e, a = 2^u, s = 3x3 box of a.
//
// r24: paired-ILP at (64,8) 512-thread blocks. r21/r23 proved hipcc
// hard-caps 1024-thr blocks at 64 VGPR (hints ignored) — the ~105-reg
// paired body can only live in a 512-thr block, where r8 measured 108
// VGPR granted spill-free. Geometry: CS=2 (32 ch/block, ty = 4 ch as
// TWO interleaved independent chains), RR=4, grid = 4x64x2 = 512 blocks
// = 2 blocks/CU -> 4 waves/SIMD TLP (same as r19) + 2-way ILP on the
// exp/shfl/hsum chains. Cost: one combine dispatch (2 planes).
// All acc indices compile-time (r15).
template <bool CHK>
__device__ __forceinline__ void do_pair(const float* __restrict__ p0,
                                        const float* __restrict__ p1,
                                        int r0, int tx, float (&acc)[RR][4]) {
  float ha0[3][4], hb0[3][4], ha1[3][4], hb1[3][4];
#pragma unroll
  for (int j = 0; j < RR + 2; ++j) {
    const int row = r0 - 1 + j;
    float4 v0 = make_float4(0.f, 0.f, 0.f, 0.f);
    float4 v1 = make_float4(0.f, 0.f, 0.f, 0.f);
    if (!CHK || (row >= 0 && row < Hh)) {
      v0 = *reinterpret_cast<const float4*>(p0 + (size_t)row * Ww);
      v1 = *reinterpret_cast<const float4*>(p1 + (size_t)row * Ww);
    }
    const float* vp0 = &v0.x;
    const float* vp1 = &v1.x;
    float a0[4], b0[4], a1[4], b1[4];
#pragma unroll
    for (int i = 0; i < 4; ++i) {
      float u0 = vp0[i] * LOG2E;
      float u1 = vp1[i] * LOG2E;
      a0[i] = __builtin_amdgcn_exp2f(u0);
      a1[i] = __builtin_amdgcn_exp2f(u1);
      b0[i] = u0 * a0[i];
      b1[i] = u1 * a1[i];
    }
    float la0 = __shfl_up(a0[3], 1, 64),  la1 = __shfl_up(a1[3], 1, 64);
    float lb0 = __shfl_up(b0[3], 1, 64),  lb1 = __shfl_up(b1[3], 1, 64);
    float ra0 = __shfl_down(a0[0], 1, 64), ra1 = __shfl_down(a1[0], 1, 64);
    float rb0 = __shfl_down(b0[0], 1, 64), rb1 = __shfl_down(b1[0], 1, 64);
    la0 = (tx == 0) ? 1.f : la0;   lb0 = (tx == 0) ? 0.f : lb0;
    la1 = (tx == 0) ? 1.f : la1;   lb1 = (tx == 0) ? 0.f : lb1;
    ra0 = (tx == 63) ? 1.f : ra0;  rb0 = (tx == 63) ? 0.f : rb0;
    ra1 = (tx == 63) ? 1.f : ra1;  rb1 = (tx == 63) ? 0.f : rb1;
    const int s0 = j % 3;  // compile-time (loop unrolled)
    {
      float t01 = a0[0] + a0[1], t23 = a0[2] + a0[3];
      ha0[s0][0] = la0 + t01;  ha0[s0][1] = t01 + a0[2];
      ha0[s0][2] = a0[1] + t23; ha0[s0][3] = t23 + ra0;
    }
    {
      float t01 = b0[0] + b0[1], t23 = b0[2] + b0[3];
      hb0[s0][0] = lb0 + t01;  hb0[s0][1] = t01 + b0[2];
      hb0[s0][2] = b0[1] + t23; hb0[s0][3] = t23 + rb0;
    }
    {
      float t01 = a1[0] + a1[1], t23 = a1[2] + a1[3];
      ha1[s0][0] = la1 + t01;  ha1[s0][1] = t01 + a1[2];
      ha1[s0][2] = a1[1] + t23; ha1[s0][3] = t23 + ra1;
    }
    {
      float t01 = b1[0] + b1[1], t23 = b1[2] + b1[3];
      hb1[s0][0] = lb1 + t01;  hb1[s0][1] = t01 + b1[2];
      hb1[s0][2] = b1[1] + t23; hb1[s0][3] = t23 + rb1;
    }
    if (j >= 2) {
      const int orow = j - 2;   // compile-time
#pragma unroll
      for (int i = 0; i < 4; ++i) {
        float s_0 = ha0[0][i] + ha0[1][i] + ha0[2][i];
        float w_0 = hb0[0][i] + hb0[1][i] + hb0[2][i];
        float s_1 = ha1[0][i] + ha1[1][i] + ha1[2][i];
        float w_1 = hb1[0][i] + hb1[1][i] + hb1[2][i];
        float e0 = __builtin_amdgcn_logf(s_0) - w_0 * __builtin_amdgcn_rcpf(s_0);
        float e1 = __builtin_amdgcn_logf(s_1) - w_1 * __builtin_amdgcn_rcpf(s_1);
        acc[orow][i] += e0 + e1;
      }
    }
  }
}

// Block (64,8): ty = 4 channels (2 ILP pairs), cs selects the 32-channel
// half. DST=0: partial -> pw[cs]; DST=1: atomicAdd fallback.
// NOTE: plain __launch_bounds__(512) — r8 measured 108 VGPR granted here.
template <int DST>
__global__ __launch_bounds__(512) void entropy_kernel(const float* __restrict__ x,
                                                      float* __restrict__ out) {
  const int bx = blockIdx.x;
  const int cs = bx & 1;
  const int strip = (bx >> 1) & (NSTRIP - 1);
  const int b = bx >> 7;
  const int r0 = strip * RR;
  const int tx = threadIdx.x;   // 0..63
  const int ty = threadIdx.y;   // 0..7
  const int w0 = tx * 4;

  const size_t planeStride = (size_t)Hh * Ww;
  const float* xb = x + ((size_t)b * Cc + cs * 32 + ty * 4) * planeStride + w0;
  const bool interior = (strip != 0) && (strip != NSTRIP - 1);

  float acc[RR][4];
#pragma unroll
  for (int o = 0; o < RR; ++o)
#pragma unroll
    for (int i = 0; i < 4; ++i) acc[o][i] = 0.f;

  if (interior) {
    do_pair<false>(xb,                   xb + planeStride,     r0, tx, acc);
    do_pair<false>(xb + 2 * planeStride, xb + 3 * planeStride, r0, tx, acc);
  } else {
    do_pair<true>(xb,                   xb + planeStride,     r0, tx, acc);
    do_pair<true>(xb + 2 * planeStride, xb + 3 * planeStride, r0, tx, acc);
  }

  // Reduce the 8 ty groups (32 KiB LDS; 2 blocks/CU -> 64 KiB/CU).
  __shared__ float red[8][RR][4][64];
#pragma unroll
  for (int o = 0; o < RR; ++o)
#pragma unroll
    for (int i = 0; i < 4; ++i) red[ty][o][i][tx] = acc[o][i];
  __syncthreads();
  if (ty < RR) {
    const size_t px = (size_t)(b * Hh + r0 + ty) * Ww + w0;
    float vsum[4];
#pragma unroll
    for (int i = 0; i < 4; ++i) {
      float t = 0.f;
#pragma unroll
      for (int g = 0; g < 8; ++g) t += red[g][ty][i][tx];
      vsum[i] = t;
    }
    if (DST == 0) {
      *reinterpret_cast<float4*>(out + (size_t)cs * NPX + px) =
          make_float4(vsum[0], vsum[1], vsum[2], vsum[3]);
    } else {
#pragma unroll
      for (int i = 0; i < 4; ++i) atomicAdd(out + px + i, vsum[i]);
    }
  }
}

// K2: combine the 2 channel-half partials, write e, emit per-block min/max
// partials (every slot written -> no init). Grid 256 x 256 threads.
__global__ __launch_bounds__(256) void combine_minmax(const float* __restrict__ pw,
                                                      float* __restrict__ e,
                                                      float* __restrict__ pm) {
  const int t = blockIdx.x * 256 + threadIdx.x;
  float4 v0 = reinterpret_cast<const float4*>(pw)[t];
  float4 v1 = reinterpret_cast<const float4*>(pw + (size_t)NPX)[t];
  float4 v = make_float4(v0.x + v1.x, v0.y + v1.y, v0.z + v1.z, v0.w + v1.w);
  reinterpret_cast<float4*>(e)[t] = v;

  float mn = fminf(fminf(v.x, v.y), fminf(v.z, v.w));
  float mx = fmaxf(fmaxf(v.x, v.y), fmaxf(v.z, v.w));
#pragma unroll
  for (int off = 32; off > 0; off >>= 1) {
    mn = fminf(mn, __shfl_down(mn, off, 64));
    mx = fmaxf(mx, __shfl_down(mx, off, 64));
  }
  __shared__ float smn[4], smx[4];
  const int wave = threadIdx.x >> 6;
  if ((threadIdx.x & 63) == 0) { smn[wave] = mn; smx[wave] = mx; }
  __syncthreads();
  if (threadIdx.x == 0) {
    pm[blockIdx.x]       = fminf(fminf(smn[0], smn[1]), fminf(smn[2], smn[3]));
    pm[256 + blockIdx.x] = fmaxf(fmaxf(smx[0], smx[1]), fmaxf(smx[2], smx[3]));
  }
}

// K3: reduce this batch's 64 min/max partials in-wave, then normalize.
__global__ __launch_bounds__(256) void norm_ws(float* __restrict__ e,
                                               const float* __restrict__ pm) {
  const int b = blockIdx.x >> 6;
  const int lane = threadIdx.x & 63;
  float mn = pm[b * 64 + lane];
  float mx = pm[256 + b * 64 + lane];
#pragma unroll
  for (int off = 32; off > 0; off >>= 1) {
    mn = fminf(mn, __shfl_down(mn, off, 64));
    mx = fmaxf(mx, __shfl_down(mx, off, 64));
  }
  mn = __shfl(mn, 0, 64);
  mx = __shfl(mx, 0, 64);
  const float inv = 1.0f / fmaxf(mx - mn, 1e-6f);

  const int t = blockIdx.x * 256 + threadIdx.x;
  float4 v = reinterpret_cast<float4*>(e)[t];
  v.x = (v.x - mn) * inv;
  v.y = (v.y - mn) * inv;
  v.z = (v.z - mn) * inv;
  v.w = (v.w - mn) * inv;
  reinterpret_cast<float4*>(e)[t] = v;
}

// Fallback path kernels (atomics + memset) — used only if ws is tiny.
__global__ __launch_bounds__(256) void minmax_atomic(const float* __restrict__ e,
                                                     unsigned int* __restrict__ stats) {
  const int bx = blockIdx.x;
  const int b = bx >> 6;
  const float4 v = reinterpret_cast<const float4*>(
      e + (size_t)b * Hh * Ww + (bx & 63) * 1024)[threadIdx.x];
  float mn = fminf(fminf(v.x, v.y), fminf(v.z, v.w));
  float mx = fmaxf(fmaxf(v.x, v.y), fmaxf(v.z, v.w));
#pragma unroll
  for (int off = 32; off > 0; off >>= 1) {
    mn = fminf(mn, __shfl_down(mn, off, 64));
    mx = fmaxf(mx, __shfl_down(mx, off, 64));
  }
  __shared__ float smn[4], smx[4];
  const int wave = threadIdx.x >> 6;
  if ((threadIdx.x & 63) == 0) { smn[wave] = mn; smx[wave] = mx; }
  __syncthreads();
  if (threadIdx.x == 0) {
    atomicMin(&stats[b], fenc(fminf(fminf(smn[0], smn[1]), fminf(smn[2], smn[3]))));
    atomicMax(&stats[4 + b], fenc(fmaxf(fmaxf(smx[0], smx[1]), fmaxf(smx[2], smx[3]))));
  }
}

__global__ __launch_bounds__(256) void norm_atomic(float* __restrict__ e,
                                                   const unsigned int* __restrict__ stats) {
  const int t = blockIdx.x * 256 + threadIdx.x;
  const int b = t >> 14;
  const float mn = fdec(stats[b]);
  const float mx = fdec(stats[4 + b]);
  const float inv = 1.0f / fmaxf(mx - mn, 1e-6f);
  float4 v = reinterpret_cast<float4*>(e)[t];
  v.x = (v.x - mn) * inv;
  v.y = (v.y - mn) * inv;
  v.z = (v.z - mn) * inv;
  v.w = (v.w - mn) * inv;
  reinterpret_cast<float4*>(e)[t] = v;
}

extern "C" void kernel_launch(void* const* d_in, const int* in_sizes, int n_in,
                              void* d_out, int out_size, void* d_ws, size_t ws_size,
                              hipStream_t stream) {
  const float* x = (const float*)d_in[0];
  float* out = (float*)d_out;

  const size_t ws_needed = ((size_t)CS * NPX + 512) * sizeof(float);  // ~2.1 MB
  if (ws_size >= ws_needed) {
    float* pw = (float*)d_ws;                 // [CS][NPX] partials
    float* pm = pw + (size_t)CS * NPX;        // [256 min][256 max]
    entropy_kernel<0><<<dim3(Bb * NSTRIP * CS), dim3(64, 8), 0, stream>>>(x, pw);
    combine_minmax<<<dim3(NPX4 / 256), dim3(256), 0, stream>>>(pw, out, pm);
    norm_ws<<<dim3(NPX4 / 256), dim3(256), 0, stream>>>(out, pm);
  } else {
    unsigned int* stats = (unsigned int*)d_ws;  // 8 uints
    hipMemsetAsync(out, 0, (size_t)NPX * sizeof(float), stream);
    hipMemsetAsync(stats, 0xFF, 4 * sizeof(unsigned int), stream);
    hipMemsetAsync(stats + 4, 0x00, 4 * sizeof(unsigned int), stream);
    entropy_kernel<1><<<dim3(Bb * NSTRIP * CS), dim3(64, 8), 0, stream>>>(x, out);
    minmax_atomic<<<dim3(Bb * 64), dim3(256), 0, stream>>>(out, stats);
    norm_atomic<<<dim3(NPX4 / 256), dim3(256), 0, stream>>>(out, stats);
  }
}

// Round 25
// 25.382 us; speedup vs baseline: 5.6761x; 1.6886x over previous
//
#include <hip/hip_runtime.h>
#include <math.h>

constexpr int Bb = 4, Cc = 64, Hh = 256, Ww = 256;
constexpr int RR = 4;             // output rows per block (amp 1.5x)
constexpr int NSTRIP = Hh / RR;   // 64
constexpr int NBLK = Bb * NSTRIP; // 256 entropy blocks = 1 per CU
constexpr int NPX = Bb * Hh * Ww; // 262144 output pixels
constexpr int NPX4 = NPX / 4;

#define LOG2E 1.44269504088896340736f

__device__ __forceinline__ unsigned int fenc(float f) {
  unsigned int u = __float_as_uint(f);
  return (u & 0x80000000u) ? ~u : (u | 0x80000000u);
}
__device__ __forceinline__ float fdec(unsigned int k) {
  return __uint_as_float((k & 0x80000000u) ? (k ^ 0x80000000u) : ~k);
}

// entropy = ln(s) - ws/s, s = 3x3 box of e^v, ws = 3x3 box of v*e^v
// (shift-invariant softmax entropy). Normalization is affine-invariant ->
// raw channel sums are normalized.
//
// FINAL (r18 structure, measured best 24.49us):
// block (64,16) = 16 waves; lane = 4 cols (float4, full 256-col row, halos
// are image edges = constants); ty = 4 channels each (rolled cc loop,
// streaming body, sliding-window hsums). RR=4 rows per block.
// Grid = b(4) x strip(64) = 256 blocks = EXACTLY 1 block/CU.
// Block holds the FULL 64-channel sum for its 4 rows -> block min/max ->
// pm[bx] non-atomic (every slot written, no init) -> single norm dispatch.
// 2 dispatches, 0 memsets, 0 atomics, no cross-block sync.
//
// Explored and rejected (measured):
//  - combine-dispatch variants (CS=2/4/8): 28-29us (r11/r18-cs8/r24)
//  - RR=2 (2.0x halo amp): 31us regardless of occupancy (r17/r22)
//  - RR=8 (1.25x amp): loses residency, 30.7us (r16)
//  - fused finish w/ cross-block sync: +12-14us (r12/r13 — fences AND
//    atomic spins are ~10us-class on 8-XCD incoherent L2s)
//  - 2-way ILP channel pairing: spills at every block shape (r21/r23/r24 —
//    hipcc caps 1024-thr blocks at 64 VGPR, hints ignored; 512-thr cap 128
//    still exceeded)
//  - min-waves launch_bounds hints: catastrophic spill (r6/r7)
//  - runtime-indexed register arrays: scratch (r15)
// Remaining time = entropy ~17us (latency-bound at geometry-capped
// 4 waves/SIMD) + norm ~3us + ~4us dispatch overhead.
template <int FB>
__global__ __launch_bounds__(1024) void entropy_kernel(const float* __restrict__ x,
                                                       float* __restrict__ e,
                                                       float* __restrict__ pm,
                                                       unsigned int* __restrict__ stats) {
  const int bx = blockIdx.x;
  const int strip = bx & (NSTRIP - 1);
  const int b = bx >> 6;
  const int r0 = strip * RR;
  const int tx = threadIdx.x;   // 0..63
  const int ty = threadIdx.y;   // 0..15
  const int w0 = tx * 4;

  const size_t planeStride = (size_t)Hh * Ww;
  const float* xb = x + ((size_t)b * Cc + ty * 4) * planeStride + w0;

  float acc[RR][4];
#pragma unroll
  for (int o = 0; o < RR; ++o)
#pragma unroll
    for (int i = 0; i < 4; ++i) acc[o][i] = 0.f;

#pragma unroll 1
  for (int cc = 0; cc < 4; ++cc) {
    const float* plane = xb + (size_t)cc * planeStride;

    float ha[3][4], hb[3][4];
#pragma unroll
    for (int j = 0; j < RR + 2; ++j) {   // stream one row at a time
      const int row = r0 - 1 + j;
      float4 v = make_float4(0.f, 0.f, 0.f, 0.f);
      if (row >= 0 && row < Hh)
        v = *reinterpret_cast<const float4*>(plane + (size_t)row * Ww);
      const float* vp = &v.x;
      float a[4], bb4[4];
#pragma unroll
      for (int i = 0; i < 4; ++i) {
        float u = vp[i] * LOG2E;
        a[i] = __builtin_amdgcn_exp2f(u);                 // e^v
        bb4[i] = u * a[i];                                // u * e^v (rescaled)
      }
      float la = __shfl_up(a[3], 1, 64);
      float lb = __shfl_up(bb4[3], 1, 64);
      float ra = __shfl_down(a[0], 1, 64);
      float rb = __shfl_down(bb4[0], 1, 64);
      la = (tx == 0) ? 1.f : la;   lb = (tx == 0) ? 0.f : lb;
      ra = (tx == 63) ? 1.f : ra;  rb = (tx == 63) ? 0.f : rb;
      // Sliding-window horizontal sums.
      const int s0 = j % 3;  // compile-time (loop unrolled)
      {
        float t01 = a[0] + a[1], t23 = a[2] + a[3];
        ha[s0][0] = la + t01;
        ha[s0][1] = t01 + a[2];
        ha[s0][2] = a[1] + t23;
        ha[s0][3] = t23 + ra;
      }
      {
        float t01 = bb4[0] + bb4[1], t23 = bb4[2] + bb4[3];
        hb[s0][0] = lb + t01;
        hb[s0][1] = t01 + bb4[2];
        hb[s0][2] = bb4[1] + t23;
        hb[s0][3] = t23 + rb;
      }
      if (j >= 2) {
        const int orow = j - 2;   // compile-time
#pragma unroll
        for (int i = 0; i < 4; ++i) {
          float s = ha[0][i] + ha[1][i] + ha[2][i];
          float w = hb[0][i] + hb[1][i] + hb[2][i];
          acc[orow][i] += __builtin_amdgcn_logf(s) -
                          w * __builtin_amdgcn_rcpf(s);
        }
      }
    }
  }

  // Reduce the 16 ty channel groups (64 KiB LDS, fine at 1 block/CU).
  __shared__ float red[16][RR][4][64];
#pragma unroll
  for (int o = 0; o < RR; ++o)
#pragma unroll
    for (int i = 0; i < 4; ++i) red[ty][o][i][tx] = acc[o][i];
  __syncthreads();

  float mn = INFINITY, mx = -INFINITY;
  if (ty < RR) {
    const size_t px = (size_t)(b * Hh + r0 + ty) * Ww + w0;
    float vsum[4];
#pragma unroll
    for (int i = 0; i < 4; ++i) {
      float t = 0.f;
#pragma unroll
      for (int g = 0; g < 16; ++g) t += red[g][ty][i][tx];
      vsum[i] = t;
    }
    *reinterpret_cast<float4*>(e + px) =
        make_float4(vsum[0], vsum[1], vsum[2], vsum[3]);
    mn = fminf(fminf(vsum[0], vsum[1]), fminf(vsum[2], vsum[3]));
    mx = fmaxf(fmaxf(vsum[0], vsum[1]), fmaxf(vsum[2], vsum[3]));
#pragma unroll
    for (int off = 32; off > 0; off >>= 1) {
      mn = fminf(mn, __shfl_down(mn, off, 64));
      mx = fmaxf(mx, __shfl_down(mx, off, 64));
    }
  }
  __shared__ float smn[RR], smx[RR];
  if (ty < RR && tx == 0) { smn[ty] = mn; smx[ty] = mx; }
  __syncthreads();
  if (ty == 0 && tx == 0) {
    mn = fminf(fminf(smn[0], smn[1]), fminf(smn[2], smn[3]));
    mx = fmaxf(fmaxf(smx[0], smx[1]), fmaxf(smx[2], smx[3]));
    if (FB == 0) {
      pm[bx] = mn;           // every slot written -> no init
      pm[NBLK + bx] = mx;
    } else {
      atomicMin(&stats[b], fenc(mn));
      atomicMax(&stats[4 + b], fenc(mx));
    }
  }
}

// Reduce this batch's 64 pm pairs in one wave, then normalize.
// Grid 256 blocks x 256 threads, one float4 per thread. Batch b = bx>>6;
// its entropy blocks are pm[b*64 .. b*64+63].
__global__ __launch_bounds__(256) void norm_ws(float* __restrict__ e,
                                               const float* __restrict__ pm) {
  const int bx = blockIdx.x;
  const int b = bx >> 6;
  const int lane = threadIdx.x & 63;
  float mn = pm[b * 64 + lane];
  float mx = pm[NBLK + b * 64 + lane];
#pragma unroll
  for (int off = 32; off > 0; off >>= 1) {
    mn = fminf(mn, __shfl_down(mn, off, 64));
    mx = fmaxf(mx, __shfl_down(mx, off, 64));
  }
  mn = __shfl(mn, 0, 64);
  mx = __shfl(mx, 0, 64);
  const float inv = 1.0f / fmaxf(mx - mn, 1e-6f);

  const int t = bx * 256 + threadIdx.x;
  float4 v = reinterpret_cast<float4*>(e)[t];
  v.x = (v.x - mn) * inv;
  v.y = (v.y - mn) * inv;
  v.z = (v.z - mn) * inv;
  v.w = (v.w - mn) * inv;
  reinterpret_cast<float4*>(e)[t] = v;
}

// Fallback normalize from atomic stats.
__global__ __launch_bounds__(256) void norm_atomic(float* __restrict__ e,
                                                   const unsigned int* __restrict__ stats) {
  const int t = blockIdx.x * 256 + threadIdx.x;
  const int b = t >> 14;
  const float mn = fdec(stats[b]);
  const float mx = fdec(stats[4 + b]);
  const float inv = 1.0f / fmaxf(mx - mn, 1e-6f);
  float4 v = reinterpret_cast<float4*>(e)[t];
  v.x = (v.x - mn) * inv;
  v.y = (v.y - mn) * inv;
  v.z = (v.z - mn) * inv;
  v.w = (v.w - mn) * inv;
  reinterpret_cast<float4*>(e)[t] = v;
}

extern "C" void kernel_launch(void* const* d_in, const int* in_sizes, int n_in,
                              void* d_out, int out_size, void* d_ws, size_t ws_size,
                              hipStream_t stream) {
  const float* x = (const float*)d_in[0];
  float* out = (float*)d_out;

  const size_t ws_needed = (size_t)(2 * NBLK) * sizeof(float);  // 2 KB
  if (ws_size >= ws_needed) {
    float* pm = (float*)d_ws;  // [NBLK min][NBLK max]
    entropy_kernel<0><<<dim3(NBLK), dim3(64, 16), 0, stream>>>(x, out, pm, nullptr);
    norm_ws<<<dim3(NPX4 / 256), dim3(256), 0, stream>>>(out, pm);
  } else {
    unsigned int* stats = (unsigned int*)d_ws;  // 8 uints
    hipMemsetAsync(stats, 0xFF, 4 * sizeof(unsigned int), stream);
    hipMemsetAsync(stats + 4, 0x00, 4 * sizeof(unsigned int), stream);
    entropy_kernel<1><<<dim3(NBLK), dim3(64, 16), 0, stream>>>(x, out, nullptr, stats);
    norm_atomic<<<dim3(NPX4 / 256), dim3(256), 0, stream>>>(out, stats);
  }
}